// Round 2
// baseline (905.178 us; speedup 1.0000x reference)
//
#include <hip/hip_runtime.h>

// ============================================================================
// WeightPopupLayer (fp32 I/O): out = x @ (W * topk_mask(|scores|, 50%))^T + b
//   x[8192,4096] f32, W[4096,4096] f32, bias[4096] f32, scores[4096,4096] f32
//   out[8192,4096] f32.
// Round-1 post-mortem: all-bf16 assumption produced NaN (fp32 misread as
// bf16 => exp-0xFF patterns). Dtypes follow the reference: float32.
// Tie semantics: stable ascending argsort of flattened |scores|; first
// j = 8388608 entries (by value, then flat index among equals) get mask 0.
// fp32 scores = 1 + 0.01*N cluster on ~1M representable values => tens of
// duplicates at the threshold; exact stable tie handling still required.
// Compute strategy: exact fp32 selection -> bf16 pruned weights + bf16 x ->
// MFMA bf16 GEMM (err ~0.025 << 0.1125 threshold) -> fp32 out + bias.
// ============================================================================

#define NTOT   16777216u    // 4096*4096
#define JDROP  8388608u     // int((1-K)*n), K=0.5
#define MDIM   8192
#define NDIM   4096
#define KDIM   4096

typedef __bf16 v8bf __attribute__((ext_vector_type(8)));
typedef float  v4f  __attribute__((ext_vector_type(4)));

__device__ __forceinline__ unsigned short f2bf(float f){
  unsigned u = __float_as_uint(f);
  u += 0x7fffu + ((u >> 16) & 1u);   // RNE
  return (unsigned short)(u >> 16);
}

// ---------------------------------------------------------------------------
// 4-pass radix select over u = bits(|s|) & 0x7FFFFFFF (monotonic in value).
// p0: u>>23 (8b) | p1: (u>>15)&0xFF | p2: (u>>7)&0xFF | p3: u&0x7F (7b)
// state[0] = accumulated prefix (after p3: full 31-bit threshold T)
// state[1] = remaining drop-target within prefix class (after p3: D ties)
// ---------------------------------------------------------------------------
__global__ void zero_hist(unsigned* hist){ hist[threadIdx.x] = 0u; }

__global__ __launch_bounds__(256) void hist_pass(const float* __restrict__ scores,
                                                 unsigned* __restrict__ hist,
                                                 const unsigned* __restrict__ state,
                                                 int p){
  // per-thread privatized byte counters pc[digit*256 + tid]; max 64/thread.
  __shared__ __align__(16) unsigned char pc[256*256];   // 64 KB
  int tid = threadIdx.x;
  unsigned* pz = (unsigned*)pc;
  #pragma unroll
  for (int k=0;k<64;++k) pz[tid + k*256] = 0u;
  __syncthreads();
  unsigned prefix = (p>0) ? state[0] : 0u;
  size_t base = (size_t)blockIdx.x * 16384;
  for (int it=0; it<64; ++it){
    unsigned u = __float_as_uint(scores[base + (size_t)it*256 + tid]) & 0x7fffffffu;
    unsigned d, ok;
    if      (p==0){ d = u>>23;         ok = 1u; }
    else if (p==1){ d = (u>>15)&0xffu; ok = ((u>>23)==prefix); }
    else if (p==2){ d = (u>>7) &0xffu; ok = ((u>>15)==prefix); }
    else          { d = u & 0x7fu;     ok = ((u>>7) ==prefix); }
    if (ok) pc[d*256 + tid]++;
  }
  __syncthreads();
  unsigned b = (unsigned)tid;          // bin b: sum 256 byte-columns
  const unsigned* row = (const unsigned*)(pc + b*256);
  unsigned s = 0;
  for (int kk=0;kk<64;++kk){
    int k = (kk + tid) & 63;           // stagger LDS banks
    unsigned w = row[k];
    s += (w & 0xffu) + ((w>>8)&0xffu) + ((w>>16)&0xffu) + (w>>24);
  }
  if (s) atomicAdd(&hist[b], s);
}

__global__ void select_pass(unsigned* hist, unsigned* state, int p){
  int lane = threadIdx.x;              // 64 threads = 1 wave
  unsigned c[4];
  #pragma unroll
  for (int k=0;k<4;++k){ c[k] = hist[lane*4+k]; hist[lane*4+k] = 0u; }
  unsigned s = c[0]+c[1]+c[2]+c[3];
  unsigned inc = s;
  #pragma unroll
  for (int d=1; d<64; d<<=1){
    unsigned t = (unsigned)__shfl_up((int)inc, d, 64);
    if (lane >= d) inc += t;
  }
  unsigned excl = inc - s;
  unsigned target = (p==0) ? JDROP : state[1];
  unsigned oldpre = (p==0) ? 0u    : state[0];
  if (target >= excl && target < excl + s){   // unique crossing lane
    unsigned cum = excl, digit = 0, below = 0;
    #pragma unroll
    for (int k=0;k<4;++k){
      if (target < cum + c[k]){ digit = (unsigned)lane*4u + (unsigned)k; below = cum; break; }
      cum += c[k];
    }
    state[0] = (oldpre << ((p==3)?7:8)) | digit;
    state[1] = target - below;
  }
}

// ---------------------------------------------------------------------------
// Stable tie ranking: per-4096-chunk tie counts -> scan -> flat-order rank.
// ---------------------------------------------------------------------------
__global__ __launch_bounds__(256) void tie_count(const float* __restrict__ scores,
                                                 const unsigned* __restrict__ state,
                                                 unsigned* __restrict__ tieCnt){
  unsigned T = state[0];
  size_t base = (size_t)blockIdx.x * 4096;
  int tid = threadIdx.x;
  unsigned cnt = 0;
  for (int it=0; it<16; ++it){
    unsigned u = __float_as_uint(scores[base + it*256 + tid]) & 0x7fffffffu;
    cnt += (u == T) ? 1u : 0u;
  }
  __shared__ unsigned r[256];
  r[tid] = cnt; __syncthreads();
  for (int s=128; s>0; s>>=1){ if (tid < s) r[tid] += r[tid+s]; __syncthreads(); }
  if (tid==0) tieCnt[blockIdx.x] = r[0];
}

__global__ __launch_bounds__(1024) void tie_scan(const unsigned* tieCnt, unsigned* tieBase){
  int tid = threadIdx.x;               // 1024 threads, 4 chunks each
  unsigned v[4], pre[4], s = 0;
  #pragma unroll
  for (int k=0;k<4;++k){ v[k] = tieCnt[tid*4+k]; pre[k] = s; s += v[k]; }
  __shared__ unsigned sc[1024];
  sc[tid] = s; __syncthreads();
  for (int d=1; d<1024; d<<=1){
    unsigned t = (tid >= d) ? sc[tid-d] : 0u;
    __syncthreads();
    sc[tid] += t;
    __syncthreads();
  }
  unsigned excl = sc[tid] - s;
  #pragma unroll
  for (int k=0;k<4;++k) tieBase[tid*4+k] = excl + pre[k];
}

__global__ __launch_bounds__(256) void build_pruned(const float* __restrict__ scores,
                                                    const float* __restrict__ w,
                                                    const unsigned* __restrict__ state,
                                                    const unsigned* __restrict__ tieBase,
                                                    unsigned short* __restrict__ wpr){
  int c = blockIdx.x;                  // one 4096-elem chunk (= one W row)
  int tid = threadIdx.x;
  int lane = tid & 63, wid = tid >> 6;
  unsigned T = state[0], D = state[1];
  __shared__ unsigned wcnt[4];
  __shared__ unsigned runBase;
  if (tid==0) runBase = tieBase[c];
  size_t base = (size_t)c * 4096;
  for (int it=0; it<16; ++it){
    size_t i = base + it*256 + tid;    // flat-order traversal
    unsigned u = __float_as_uint(scores[i]) & 0x7fffffffu;
    bool tie = (u == T), gt = (u > T);
    unsigned long long b = __ballot(tie);
    unsigned lanePre = (unsigned)__popcll(b & ((1ull << lane) - 1ull));
    if (lane==0) wcnt[wid] = (unsigned)__popcll(b);
    __syncthreads();                   // wcnt ready; runBase stable
    unsigned off = 0;
    #pragma unroll
    for (int ww=0; ww<4; ++ww) if (ww < wid) off += wcnt[ww];
    unsigned tot = wcnt[0]+wcnt[1]+wcnt[2]+wcnt[3];
    unsigned rank = runBase + off + lanePre;   // global flat-order tie rank
    bool keep = gt || (tie && rank >= D);      // first D ties dropped
    wpr[i] = keep ? f2bf(w[i]) : (unsigned short)0;
    __syncthreads();                   // all reads of runBase done
    if (tid==0) runBase += tot;
  }
}

// ---------------------------------------------------------------------------
// x fp32 -> bf16
// ---------------------------------------------------------------------------
__global__ __launch_bounds__(256) void convert_x(const float4* __restrict__ x,
                                                 ushort4* __restrict__ xb){
  size_t i = (size_t)blockIdx.x * 256 + threadIdx.x;   // one float4 each
  float4 v = x[i];
  ushort4 o; o.x=f2bf(v.x); o.y=f2bf(v.y); o.z=f2bf(v.z); o.w=f2bf(v.w);
  xb[i] = o;
}

// ---------------------------------------------------------------------------
// GEMM: out[m,n] = sum_k xb[m,k]*wpr[n,k] + bias[n]; fp32 out.
// m97 structure: 128x128 tile, BK=32, 4 waves 2x2, 4x4 MFMA tiles/wave,
// global_load_lds dwordx4 staging, mfma_f32_16x16x32_bf16.
// ---------------------------------------------------------------------------
__device__ __forceinline__ void gload_lds16(const void* g, void* l){
  __builtin_amdgcn_global_load_lds(
      (__attribute__((address_space(1))) void*)g,
      (__attribute__((address_space(3))) void*)l, 16, 0, 0);
}

__global__ __launch_bounds__(256) void gemm_bt(const unsigned short* __restrict__ A, // xb bf16 [M,K]
                                               const unsigned short* __restrict__ B, // wpr bf16 [N,K]
                                               const float* __restrict__ bias,
                                               float* __restrict__ out){
  const int Nb = blockIdx.x * 128;
  const int Mb = blockIdx.y * 128;
  const int tid  = threadIdx.x;
  const int lane = tid & 63;
  const int wid  = tid >> 6;
  const int wr = wid >> 1, wc = wid & 1;

  __shared__ __align__(16) unsigned short As[128*32];  // 8 KB
  __shared__ __align__(16) unsigned short Bs[128*32];  // 8 KB

  v4f acc[4][4];
  #pragma unroll
  for (int mt=0; mt<4; ++mt)
    #pragma unroll
    for (int nt=0; nt<4; ++nt) acc[mt][nt] = (v4f){0.f,0.f,0.f,0.f};

  const int ldrow = (lane >> 2);        // 0..15 within 16-row group
  const int ldcol = (lane & 3) * 8;     // bf16 elem offset (16 B)

  for (int kt=0; kt<KDIM/32; ++kt){
    const int k0 = kt * 32;
    #pragma unroll
    for (int i=0; i<2; ++i){
      const int rb = i*64 + wid*16;     // wave-uniform row base
      gload_lds16(A + (size_t)(Mb + rb + ldrow)*KDIM + k0 + ldcol, &As[rb*32]);
      gload_lds16(B + (size_t)(Nb + rb + ldrow)*KDIM + k0 + ldcol, &Bs[rb*32]);
    }
    __syncthreads();                    // drains vmcnt before LDS reads

    const int ar = lane & 15;
    const int kg = (lane >> 4) * 8;
    v8bf af[4], bfv[4];
    #pragma unroll
    for (int mt=0; mt<4; ++mt) af[mt]  = *(const v8bf*)&As[(wr*64 + mt*16 + ar)*32 + kg];
    #pragma unroll
    for (int nt=0; nt<4; ++nt) bfv[nt] = *(const v8bf*)&Bs[(wc*64 + nt*16 + ar)*32 + kg];
    #pragma unroll
    for (int mt=0; mt<4; ++mt)
      #pragma unroll
      for (int nt=0; nt<4; ++nt)
        acc[mt][nt] = __builtin_amdgcn_mfma_f32_16x16x32_bf16(af[mt], bfv[nt], acc[mt][nt], 0, 0, 0);
    __syncthreads();                    // before next stage overwrites LDS
  }

  // epilogue: C/D layout col(n) = lane&15, row(m) = (lane>>4)*4 + r
  #pragma unroll
  for (int mt=0; mt<4; ++mt){
    const int gm0 = Mb + wr*64 + mt*16 + (lane >> 4)*4;
    #pragma unroll
    for (int nt=0; nt<4; ++nt){
      const int gn = Nb + wc*64 + nt*16 + (lane & 15);
      const float bv = bias[gn];
      v4f a = acc[mt][nt];
      #pragma unroll
      for (int r=0; r<4; ++r)
        out[(size_t)(gm0 + r)*NDIM + gn] = a[r] + bv;
    }
  }
}

// ---------------------------------------------------------------------------
extern "C" void kernel_launch(void* const* d_in, const int* in_sizes, int n_in,
                              void* d_out, int out_size, void* d_ws, size_t ws_size,
                              hipStream_t stream){
  const float* x      = (const float*)d_in[0];
  const float* w      = (const float*)d_in[1];
  const float* bias   = (const float*)d_in[2];
  const float* scores = (const float*)d_in[3];
  float* out = (float*)d_out;

  char* ws = (char*)d_ws;
  unsigned* hist    = (unsigned*)(ws);                 // 1 KB
  unsigned* state   = (unsigned*)(ws + 1024);          // {prefix/T, target/D}
  unsigned* tieCnt  = (unsigned*)(ws + 2048);          // 16 KB
  unsigned* tieBase = (unsigned*)(ws + 2048 + 16384);  // 16 KB
  unsigned short* xb  = (unsigned short*)(ws + 65536);              // 64 MB
  unsigned short* wpr = (unsigned short*)(ws + 65536 + (size_t)MDIM*KDIM*2); // 32 MB

  zero_hist<<<1, 256, 0, stream>>>(hist);
  for (int p = 0; p < 4; ++p){
    hist_pass<<<1024, 256, 0, stream>>>(scores, hist, state, p);
    select_pass<<<1, 64, 0, stream>>>(hist, state, p);
  }
  tie_count<<<4096, 256, 0, stream>>>(scores, state, tieCnt);
  tie_scan<<<1, 1024, 0, stream>>>(tieCnt, tieBase);
  build_pruned<<<4096, 256, 0, stream>>>(scores, w, state, tieBase, wpr);
  convert_x<<<MDIM*KDIM/4/256, 256, 0, stream>>>((const float4*)x, (ushort4*)xb);

  gemm_bt<<<dim3(NDIM/128, MDIM/128), 256, 0, stream>>>(xb, wpr, bias, out);
}